// Round 11
// baseline (230.036 us; speedup 1.0000x reference)
//
#include <hip/hip_runtime.h>
#include <hip/hip_bf16.h>
#include <cstdint>
#include <cstddef>

#define B_ 2
#define S_ 2048
#define D_ 1024
#define H_ 16
#define HD_ 64
#define M_ 4096   // B_*S_

typedef __attribute__((ext_vector_type(8))) short short8;
typedef __attribute__((ext_vector_type(4))) float floatx4;
typedef __attribute__((ext_vector_type(16))) float f32x16;
typedef __attribute__((ext_vector_type(2))) int intx2;

__device__ __forceinline__ f32x16 mfma3216(short8 a, short8 b, f32x16 c) {
    return __builtin_amdgcn_mfma_f32_32x32x16_bf16(a, b, c, 0, 0, 0);
}

// async global->LDS, 16B per lane; lds base wave-uniform, lane i lands at base + i*16B
__device__ __forceinline__ void gload_lds16(const __hip_bfloat16* g, __hip_bfloat16* lds_base) {
    __builtin_amdgcn_global_load_lds(
        (const __attribute__((address_space(1))) void*)g,
        (__attribute__((address_space(3))) void*)lds_base, 16, 0, 0);
}

// pack two f32 -> one dword of 2 bf16
__device__ __forceinline__ int pkbf(float a, float b) {
    union { __hip_bfloat162 h; int i; } u;
    u.h = __float22bfloat162_rn({a, b});
    return u.i;
}
// permlane32_swap: a[lanes>=32] <-> b[lanes<32] (T12 recipe; HW-verified R4/R6)
__device__ __forceinline__ void pl32swap(int& a, int& b) {
    intx2 r = __builtin_amdgcn_permlane32_swap(a, b, false, false);
    a = r.x; b = r.y;
}

// ---------------- merged converter: fp32 -> bf16 (inputs + weights) + mask->bias ----------
// grid.x = 3*4096 (inputs) + 4*1024 (weights) + 4 (mask bias) = 16388
__global__ __launch_bounds__(256) void cvt_all_kernel(
    const float* __restrict__ q, const float* __restrict__ k, const float* __restrict__ v,
    const float* __restrict__ wq, const float* __restrict__ wk,
    const float* __restrict__ wv, const float* __restrict__ wo,
    const int* __restrict__ mask,
    __hip_bfloat16* __restrict__ dstIn,   // 3 x SZ_IN
    __hip_bfloat16* __restrict__ dstW,    // 4 x SZ_W
    float* __restrict__ fbias)            // B_*S_
{
    const int bid = blockIdx.x;
    const int tid = threadIdx.x;
    const size_t SZ_IN = (size_t)M_ * D_;
    const size_t SZ_W  = (size_t)D_ * D_;
    if (bid < 12288) {
        int z = bid >> 12, xb = bid & 4095;
        const float* src = z == 0 ? q : z == 1 ? k : v;
        __hip_bfloat16* d = dstIn + (size_t)z * SZ_IN;
        int i = (xb * 256 + tid) * 4;
        float4 val = *(const float4*)(src + i);
        union { __hip_bfloat16 h[4]; uint2 u; } cv;
        cv.h[0] = __float2bfloat16(val.x); cv.h[1] = __float2bfloat16(val.y);
        cv.h[2] = __float2bfloat16(val.z); cv.h[3] = __float2bfloat16(val.w);
        *(uint2*)(d + i) = cv.u;
    } else if (bid < 16384) {
        int r  = bid - 12288;
        int z  = r >> 10, xb = r & 1023;
        const float* src = z == 0 ? wq : z == 1 ? wk : z == 2 ? wv : wo;
        __hip_bfloat16* d = dstW + (size_t)z * SZ_W;
        int i = (xb * 256 + tid) * 4;
        float4 val = *(const float4*)(src + i);
        union { __hip_bfloat16 h[4]; uint2 u; } cv;
        cv.h[0] = __float2bfloat16(val.x); cv.h[1] = __float2bfloat16(val.y);
        cv.h[2] = __float2bfloat16(val.z); cv.h[3] = __float2bfloat16(val.w);
        *(uint2*)(d + i) = cv.u;
    } else {
        int i = ((bid - 16384) * 256 + tid) * 4;   // 4096 ints over 4 blocks
        int4 m = *(const int4*)(mask + i);
        float4 o;
        o.x = m.x ? -100000.0f : 0.0f;
        o.y = m.y ? -100000.0f : 0.0f;
        o.z = m.z ? -100000.0f : 0.0f;
        o.w = m.w ? -100000.0f : 0.0f;
        *(float4*)(fbias + i) = o;
    }
}

// ---------------- GEMM core 128x128: C = A[M,K] @ W[N,K]^T + bias ----------------
// BK=32, 256 threads (4 waves, 64x64 quadrant each), global_load_lds staging.
// 32x32x16 MFMA (R11): half the MFMA instruction count of 16x16x32 at equal FLOP,
// same LDS-read count, same 64-f32 accumulator. Layouts HW-verified in this session's
// flash kernel (A/B-frag row=l&31 k=hi*8+j; C/D crow=(r&3)+8*(r>>2)+4*hi).
// MODE 0: bf16 row-major. MODE 1: bf16 V^T (Vt[b,h,e,s], packed 8B stores).
template <int MODE>
__device__ __forceinline__ void gemm_core(
    const __hip_bfloat16* __restrict__ A,
    const __hip_bfloat16* __restrict__ W,
    const float* __restrict__ bias,
    void* __restrict__ Cout,
    __hip_bfloat16* __restrict__ smem,   // 2*128*32 bf16
    int m0, int n0, int N)
{
    __hip_bfloat16* As = smem;
    __hip_bfloat16* Bs = smem + 128 * 32;
    const int K = D_;
    const int tid  = threadIdx.x;
    const int wave = tid >> 6;
    const int lane = tid & 63;
    const int l31  = lane & 31;
    const int hi   = lane >> 5;
    const int wm   = (wave & 1) * 64;
    const int wn   = (wave >> 1) * 64;
    const int srow = lane >> 2;
    const int scol = (lane & 3) * 8;

    f32x16 acc[2][2];
#pragma unroll
    for (int i = 0; i < 2; i++)
#pragma unroll
        for (int j = 0; j < 2; j++)
#pragma unroll
            for (int r = 0; r < 16; r++) acc[i][j][r] = 0.f;

    for (int k0 = 0; k0 < K; k0 += 32) {
        __syncthreads();
#pragma unroll
        for (int t = 0; t < 2; t++) {
            int r0 = wave * 32 + t * 16;
            gload_lds16(A + (size_t)(m0 + r0 + srow) * K + k0 + scol, As + r0 * 32);
            gload_lds16(W + (size_t)(n0 + r0 + srow) * K + k0 + scol, Bs + r0 * 32);
        }
        __syncthreads();

        short8 afr[2][2], bfr[2][2];   // [blk][k-half]
#pragma unroll
        for (int mb = 0; mb < 2; mb++)
#pragma unroll
            for (int kh = 0; kh < 2; kh++)
                afr[mb][kh] = *(const short8*)(As + (wm + mb * 32 + l31) * 32 + kh * 16 + hi * 8);
#pragma unroll
        for (int nb = 0; nb < 2; nb++)
#pragma unroll
            for (int kh = 0; kh < 2; kh++)
                bfr[nb][kh] = *(const short8*)(Bs + (wn + nb * 32 + l31) * 32 + kh * 16 + hi * 8);
#pragma unroll
        for (int kh = 0; kh < 2; kh++)
#pragma unroll
            for (int mb = 0; mb < 2; mb++)
#pragma unroll
                for (int nb = 0; nb < 2; nb++)
                    acc[mb][nb] = mfma3216(afr[mb][kh], bfr[nb][kh], acc[mb][nb]);
    }

    if constexpr (MODE == 1) {
        // V^T out: Vt[((b*H+h)*64+e)*S + s]; rows (r&3) consecutive -> pack 4 into 8B
#pragma unroll
        for (int nb = 0; nb < 2; nb++) {
            int col = n0 + wn + nb * 32 + l31;
            int h = col >> 6, e = col & 63;
            float bv = bias[col];
#pragma unroll
            for (int mb = 0; mb < 2; mb++)
#pragma unroll
                for (int rq = 0; rq < 4; rq++) {
                    int s0 = m0 + wm + mb * 32 + rq * 8 + hi * 4;
                    int bb = s0 >> 11, sl = s0 & 2047;
                    union { __hip_bfloat16 hx[4]; uint2 u; } pk;
#pragma unroll
                    for (int j = 0; j < 4; j++)
                        pk.hx[j] = __float2bfloat16(acc[mb][nb][rq * 4 + j] + bv);
                    *(uint2*)((__hip_bfloat16*)Cout + (((size_t)bb * H_ + h) * HD_ + e) * S_ + sl) = pk.u;
                }
        }
    } else {
#pragma unroll
        for (int nb = 0; nb < 2; nb++) {
            int col = n0 + wn + nb * 32 + l31;
            float bv = bias[col];
#pragma unroll
            for (int mb = 0; mb < 2; mb++)
#pragma unroll
                for (int r = 0; r < 16; r++) {
                    int rowg = m0 + wm + mb * 32 + (r & 3) + 8 * (r >> 2) + hi * 4;
                    ((__hip_bfloat16*)Cout)[(size_t)rowg * N + col] =
                        __float2bfloat16(acc[mb][nb][r] + bv);
                }
        }
    }
}

// fused QKV projections: grid (8, 32, 3). XCD-chunked swizzle (T1, proven R7:
// FETCH 69.7 -> 12.4 MB).
__global__ __launch_bounds__(256) void qkv_gemm_kernel(
    const __hip_bfloat16* __restrict__ qb, const __hip_bfloat16* __restrict__ kb,
    const __hip_bfloat16* __restrict__ vb,
    const __hip_bfloat16* __restrict__ Wqb, const __hip_bfloat16* __restrict__ Wkb,
    const __hip_bfloat16* __restrict__ Wvb,
    const float* __restrict__ bq, const float* __restrict__ bk, const float* __restrict__ bv,
    __hip_bfloat16* __restrict__ Qp, __hip_bfloat16* __restrict__ Kp,
    __hip_bfloat16* __restrict__ Vt)
{
    __shared__ __hip_bfloat16 smem[2 * 128 * 32] __attribute__((aligned(16)));
    const int z = blockIdx.z;
    const __hip_bfloat16* A = z == 0 ? qb : z == 1 ? kb : vb;
    const __hip_bfloat16* W = z == 0 ? Wqb : z == 1 ? Wkb : Wvb;
    const float* bias = z == 0 ? bq : z == 1 ? bk : bv;
    int lin  = blockIdx.y * 8 + blockIdx.x;          // 0..255
    int work = (lin & 7) * 32 + (lin >> 3);          // bijective XCD-chunked
    int m0 = (work >> 3) * 128, n0 = (work & 7) * 128;
    if (z < 2) gemm_core<0>(A, W, bias, z == 0 ? (void*)Qp : (void*)Kp, smem, m0, n0, D_);
    else       gemm_core<1>(A, W, bias, (void*)Vt, smem, m0, n0, D_);
}

// ---------------- output projection: 64x128 tile, fp32 out. grid (8, 64) ----------------
__global__ __launch_bounds__(256) void oproj_gemm_kernel(
    const __hip_bfloat16* __restrict__ A, const __hip_bfloat16* __restrict__ W,
    const float* __restrict__ bias, float* __restrict__ out)
{
    __shared__ __hip_bfloat16 As[64 * 32]  __attribute__((aligned(16)));
    __shared__ __hip_bfloat16 Bs[128 * 32] __attribute__((aligned(16)));
    const int K = D_, N = D_;
    const int tid  = threadIdx.x;
    int lin  = blockIdx.y * 8 + blockIdx.x;          // 0..511
    int work = (lin & 7) * 64 + (lin >> 3);          // XCD-chunked swizzle
    const int m0   = (work >> 3) * 64;
    const int n0   = (work & 7) * 128;
    const int wave = tid >> 6;
    const int lane = tid & 63;
    const int l31  = lane & 31;
    const int hi   = lane >> 5;
    const int wm   = (wave & 1) * 32;
    const int wn   = (wave >> 1) * 64;
    const int srow = lane >> 2;
    const int scol = (lane & 3) * 8;

    f32x16 acc[2];
#pragma unroll
    for (int j = 0; j < 2; j++)
#pragma unroll
        for (int r = 0; r < 16; r++) acc[j][r] = 0.f;

    for (int k0 = 0; k0 < K; k0 += 32) {
        __syncthreads();
        {
            int ra = wave * 16;   // A: 64 rows, 1 gload/wave
            gload_lds16(A + (size_t)(m0 + ra + srow) * K + k0 + scol, As + ra * 32);
#pragma unroll
            for (int t = 0; t < 2; t++) {
                int rb = wave * 32 + t * 16;  // B: 128 rows, 2 gloads/wave
                gload_lds16(W + (size_t)(n0 + rb + srow) * K + k0 + scol, Bs + rb * 32);
            }
        }
        __syncthreads();

        short8 afr[2], bfr[2][2];
#pragma unroll
        for (int kh = 0; kh < 2; kh++)
            afr[kh] = *(const short8*)(As + (wm + l31) * 32 + kh * 16 + hi * 8);
#pragma unroll
        for (int nb = 0; nb < 2; nb++)
#pragma unroll
            for (int kh = 0; kh < 2; kh++)
                bfr[nb][kh] = *(const short8*)(Bs + (wn + nb * 32 + l31) * 32 + kh * 16 + hi * 8);
#pragma unroll
        for (int kh = 0; kh < 2; kh++)
#pragma unroll
            for (int nb = 0; nb < 2; nb++)
                acc[nb] = mfma3216(afr[kh], bfr[nb][kh], acc[nb]);
    }

#pragma unroll
    for (int nb = 0; nb < 2; nb++) {
        int col = n0 + wn + nb * 32 + l31;
        float bv = bias[col];
#pragma unroll
        for (int r = 0; r < 16; r++) {
            int rowg = m0 + wm + (r & 3) + 8 * (r >> 2) + hi * 4;
            out[(size_t)rowg * N + col] = acc[nb][r] + bv;
        }
    }
}

// ---------------- flash attention v11 (R9, proven 52.8 us): R6 + V-frag hoist -----------
// 512 thr = 8 waves (qw=warp&3 q-block, kvh=warp>>2 kv-half), KVBLK=64, 32x32 MFMA,
// swapped QK^T, in-register P (cvt_pk+permlane32_swap), dbuf K/V + reg prefetch, ONE
// barrier per tile, XCD-chunked swizzle, V-frag hoist. R10 lesson: SM->PV splitting
// serializes the exp2 chains (bulk SM has more VALU ILP) — keep bulk SM.
#define LDP 72
#define NTK (S_ / 64)
#define KVBUF (64 * LDP)
__global__ __launch_bounds__(512, 4) void flash_attn_kernel(
    const __hip_bfloat16* __restrict__ Q,   // [B,S,D] bf16
    const __hip_bfloat16* __restrict__ Kp,  // [B,S,D] bf16
    const __hip_bfloat16* __restrict__ Vt,  // [B,H,64,S] bf16
    const float* __restrict__ fbias,        // [B,S] additive bias (0 or -1e5)
    __hip_bfloat16* __restrict__ O)         // [B,S,D]
{
    __shared__ __hip_bfloat16 smem[4 * KVBUF] __attribute__((aligned(16)));
    // layout: [0,1) KsB0, [1,2) KsB1, [2,3) VtsB0, [3,4) VtsB1  (units of KVBUF)

    const int tid  = threadIdx.x;
    int lin  = blockIdx.y * 16 + blockIdx.x;        // 0..511
    int work = (lin & 7) * 64 + (lin >> 3);         // XCD-chunked swizzle
    const int q0   = (work & 15) * 128;
    const int bh   = work >> 4;
    const int b    = bh >> 4;
    const int h    = bh & 15;
    const int warp = tid >> 6;
    const int qw   = warp & 3;     // q-block
    const int kvh  = warp >> 2;    // kv half of each tile
    const int lane = tid & 63;
    const int l31  = lane & 31;
    const int hi   = lane >> 5;
    const float kSc = 0.18033688f;  // 0.125 * log2(e)

    // ---- stage Q (128x64) coalesced into smem base, read frags, release ----
    const size_t baseQ = ((size_t)b * S_ + q0) * D_ + (size_t)h * HD_;
#pragma unroll
    for (int c = tid; c < 1024; c += 512) {
        int row = c >> 3, kc = c & 7;
        *(uint4*)(smem + row * LDP + kc * 8) =
            *(const uint4*)(Q + baseQ + (size_t)row * D_ + kc * 8);
    }
    __syncthreads();
    short8 qb[4];   // B-frag: n=q=l31, k(hd) = ks*16 + hi*8 + j
#pragma unroll
    for (int ks = 0; ks < 4; ks++)
        qb[ks] = *(const short8*)(smem + (qw * 32 + l31) * LDP + ks * 16 + hi * 8);
    __syncthreads();   // all frag reads done before staging overwrites smem

    const float* brow = fbias + b * S_;
    const __hip_bfloat16* VtBase = Vt + (size_t)bh * HD_ * S_;
    const size_t baseKrow = (size_t)b * S_ * D_ + (size_t)h * HD_;

    // prefetch staging: 512 threads cover one 64x64 tile of K and of Vt, 1 uint4 each
    const int r0  = tid >> 3;          // 0..63
    const int kc0 = (tid & 7) * 8;

    uint4 kreg, vreg;
    auto issue = [&](int kv0) {
        kreg = *(const uint4*)(Kp + baseKrow + (size_t)(kv0 + r0) * D_ + kc0);
        vreg = *(const uint4*)(VtBase + (size_t)r0 * S_ + kv0 + kc0);
    };
    auto commit = [&](int pb) {
        *(uint4*)(smem + pb * KVBUF + r0 * LDP + kc0) = kreg;
        *(uint4*)(smem + (2 + pb) * KVBUF + r0 * LDP + kc0) = vreg;
    };

    issue(0);
    commit(0);
    __syncthreads();

    float lsum = 0.f;
    f32x16 o_acc[2];
#pragma unroll
    for (int hdb = 0; hdb < 2; hdb++)
#pragma unroll
        for (int r = 0; r < 16; r++) o_acc[hdb][r] = 0.f;

    for (int t = 0; t < NTK; ++t) {
        if (t) __syncthreads();   // buf[t&1] commits visible; prev readers ordered

        if (t + 1 < NTK) issue((t + 1) * 64);

        const __hip_bfloat16* Ks  = smem + (t & 1) * KVBUF;
        const __hip_bfloat16* Vts = smem + (2 + (t & 1)) * KVBUF;

        // hoist V B-frags: 4 independent ds_reads that complete under the QK chain
        short8 vfr[4];
#pragma unroll
        for (int hdb = 0; hdb < 2; hdb++)
#pragma unroll
            for (int ksl = 0; ksl < 2; ksl++)
                vfr[hdb * 2 + ksl] = *(const short8*)(Vts + (hdb * 32 + l31) * LDP +
                                                      kvh * 32 + ksl * 16 + hi * 8);

        // S^T = K.Q^T for this wave's kv half: 4 chained MFMAs
        f32x16 z;
#pragma unroll
        for (int r = 0; r < 16; r++) z[r] = 0.f;
        __builtin_amdgcn_s_setprio(1);
#pragma unroll
        for (int ks = 0; ks < 4; ks++) {
            short8 ka = *(const short8*)(Ks + (kvh * 32 + l31) * LDP + ks * 16 + hi * 8);
            z = mfma3216(ka, qb[ks], z);
        }
        __builtin_amdgcn_s_setprio(0);

        // softmax numerator + pack, 8 values (one 16-kv slice) at a time
        short8 pa[2];
#pragma unroll
        for (int ksl = 0; ksl < 2; ksl++) {
            // bias: p[i] needs kv = t*64 + kvh*32 + ksl*16 + (i>>2)*8 + (i&3) + 4*hi
            const float* bb = brow + t * 64 + kvh * 32 + ksl * 16 + hi * 4;
            floatx4 b0 = *(const floatx4*)(bb);
            floatx4 b1 = *(const floatx4*)(bb + 8);
            float p[8];
#pragma unroll
            for (int i = 0; i < 8; i++) {
                float bias = (i < 4) ? b0[i & 3] : b1[i & 3];
                p[i] = __builtin_amdgcn_exp2f(z[ksl * 8 + i] * kSc + bias);
            }
            lsum += ((p[0] + p[1]) + (p[2] + p[3])) + ((p[4] + p[5]) + (p[6] + p[7]));
            int w0 = pkbf(p[0], p[1]);
            int w2 = pkbf(p[4], p[5]);
            int w1 = pkbf(p[2], p[3]);
            int w3 = pkbf(p[6], p[7]);
            pl32swap(w0, w2);
            pl32swap(w1, w3);
            union { int w[4]; short8 s; } fr;
            fr.w[0] = w0; fr.w[1] = w1; fr.w[2] = w2; fr.w[3] = w3;
            pa[ksl] = fr.s;
        }

        // O += P @ V over this kv half: operands already in registers (vfr)
        __builtin_amdgcn_s_setprio(1);
#pragma unroll
        for (int hdb = 0; hdb < 2; hdb++)
#pragma unroll
            for (int ksl = 0; ksl < 2; ksl++)
                o_acc[hdb] = mfma3216(pa[ksl], vfr[hdb * 2 + ksl], o_acc[hdb]);
        __builtin_amdgcn_s_setprio(0);

        if (t + 1 < NTK) commit((t + 1) & 1);   // safe: prev readers barrier-ordered
    }

    // ---- combine kv-half partials across wave pairs (w, w+4) via LDS ----
    __syncthreads();   // all LDS tile reads done; smem reusable as scratch
    float* ored = (float*)smem;            // [32 slots][256 lanes] = 32 KB
    float* lred = (float*)smem + 8192;     // [256]
    if (kvh == 1) {
#pragma unroll
        for (int hdb = 0; hdb < 2; hdb++)
#pragma unroll
            for (int r = 0; r < 16; r++)
                ored[(hdb * 16 + r) * 256 + qw * 64 + lane] = o_acc[hdb][r];
        lred[qw * 64 + lane] = lsum;
    }
    __syncthreads();
    if (kvh == 0) {
#pragma unroll
        for (int hdb = 0; hdb < 2; hdb++)
#pragma unroll
            for (int r = 0; r < 16; r++)
                o_acc[hdb][r] += ored[(hdb * 16 + r) * 256 + qw * 64 + lane];
        float ls = lsum + lred[qw * 64 + lane];
        ls += __shfl_xor(ls, 32);
        float inv = 1.0f / ls;

        const size_t baseO = ((size_t)b * S_ + q0 + qw * 32) * D_ + (size_t)h * HD_;
#pragma unroll
        for (int r = 0; r < 16; r++) {
            int crow = (r & 3) + 8 * (r >> 2) + 4 * hi;   // q row for this reg
            float iv = __shfl(inv, crow);
#pragma unroll
            for (int hdb = 0; hdb < 2; hdb++)
                O[baseO + (size_t)crow * D_ + hdb * 32 + l31] =
                    __float2bfloat16(o_acc[hdb][r] * iv);
        }
    }
}

extern "C" void kernel_launch(void* const* d_in, const int* in_sizes, int n_in,
                              void* d_out, int out_size, void* d_ws, size_t ws_size,
                              hipStream_t stream) {
    const float* query = (const float*)d_in[0];
    const float* key   = (const float*)d_in[1];
    const float* value = (const float*)d_in[2];
    const int*   mask  = (const int*)d_in[3];
    const float* Wq    = (const float*)d_in[4];
    const float* bq    = (const float*)d_in[5];
    const float* Wk    = (const float*)d_in[6];
    const float* bk    = (const float*)d_in[7];
    const float* Wv    = (const float*)d_in[8];
    const float* bv    = (const float*)d_in[9];
    const float* Wo    = (const float*)d_in[10];
    const float* bo    = (const float*)d_in[11];
    float* out = (float*)d_out;

    const size_t SZ_IN = (size_t)M_ * D_;
    const size_t SZ_W  = (size_t)D_ * D_;
    __hip_bfloat16* qb  = (__hip_bfloat16*)d_ws;
    __hip_bfloat16* kb  = qb  + SZ_IN;
    __hip_bfloat16* vb  = kb  + SZ_IN;
    __hip_bfloat16* Wqb = vb  + SZ_IN;
    __hip_bfloat16* Wkb = Wqb + SZ_W;
    __hip_bfloat16* Wvb = Wkb + SZ_W;
    __hip_bfloat16* Wob = Wvb + SZ_W;
    __hip_bfloat16* Qp  = Wob + SZ_W;
    __hip_bfloat16* Kp  = Qp  + SZ_IN;
    __hip_bfloat16* Vt  = Kp  + SZ_IN;      // [B,H,64,S]
    float*          fb  = (float*)(Vt + SZ_IN);  // [B,S] additive softmax bias

    cvt_all_kernel<<<dim3(16388), 256, 0, stream>>>(
        query, key, value, Wq, Wk, Wv, Wo, mask, qb, Wqb, fb);

    qkv_gemm_kernel<<<dim3(D_ / 128, M_ / 128, 3), 256, 0, stream>>>(
        qb, kb, vb, Wqb, Wkb, Wvb, bq, bk, bv, Qp, Kp, Vt);

    flash_attn_kernel<<<dim3(S_ / 128, B_ * H_), 512, 0, stream>>>(Qp, Kp, Vt, fb, Qp);

    oproj_gemm_kernel<<<dim3(D_ / 128, M_ / 64), 256, 0, stream>>>(Qp, Wob, bo, out);
}

// Round 12
// 219.355 us; speedup vs baseline: 1.0487x; 1.0487x over previous
//
#include <hip/hip_runtime.h>
#include <hip/hip_bf16.h>
#include <cstdint>
#include <cstddef>

#define B_ 2
#define S_ 2048
#define D_ 1024
#define H_ 16
#define HD_ 64
#define M_ 4096   // B_*S_

typedef __attribute__((ext_vector_type(8))) short short8;
typedef __attribute__((ext_vector_type(4))) float floatx4;
typedef __attribute__((ext_vector_type(16))) float f32x16;
typedef __attribute__((ext_vector_type(2))) int intx2;

__device__ __forceinline__ floatx4 mfma32(short8 a, short8 b, floatx4 c) {
    return __builtin_amdgcn_mfma_f32_16x16x32_bf16(a, b, c, 0, 0, 0);
}
__device__ __forceinline__ f32x16 mfma3216(short8 a, short8 b, f32x16 c) {
    return __builtin_amdgcn_mfma_f32_32x32x16_bf16(a, b, c, 0, 0, 0);
}

// async global->LDS, 16B per lane; lds base wave-uniform, lane i lands at base + i*16B
__device__ __forceinline__ void gload_lds16(const __hip_bfloat16* g, __hip_bfloat16* lds_base) {
    __builtin_amdgcn_global_load_lds(
        (const __attribute__((address_space(1))) void*)g,
        (__attribute__((address_space(3))) void*)lds_base, 16, 0, 0);
}

// pack two f32 -> one dword of 2 bf16
__device__ __forceinline__ int pkbf(float a, float b) {
    union { __hip_bfloat162 h; int i; } u;
    u.h = __float22bfloat162_rn({a, b});
    return u.i;
}
// permlane32_swap: a[lanes>=32] <-> b[lanes<32] (T12 recipe; HW-verified R4/R6)
__device__ __forceinline__ void pl32swap(int& a, int& b) {
    intx2 r = __builtin_amdgcn_permlane32_swap(a, b, false, false);
    a = r.x; b = r.y;
}

// ---------------- merged converter: fp32 -> bf16 (inputs + weights) + mask->bias ----------
// grid.x = 3*4096 (inputs) + 4*1024 (weights) + 4 (mask bias) = 16388
__global__ __launch_bounds__(256) void cvt_all_kernel(
    const float* __restrict__ q, const float* __restrict__ k, const float* __restrict__ v,
    const float* __restrict__ wq, const float* __restrict__ wk,
    const float* __restrict__ wv, const float* __restrict__ wo,
    const int* __restrict__ mask,
    __hip_bfloat16* __restrict__ dstIn,   // 3 x SZ_IN
    __hip_bfloat16* __restrict__ dstW,    // 4 x SZ_W
    float* __restrict__ fbias)            // B_*S_
{
    const int bid = blockIdx.x;
    const int tid = threadIdx.x;
    const size_t SZ_IN = (size_t)M_ * D_;
    const size_t SZ_W  = (size_t)D_ * D_;
    if (bid < 12288) {
        int z = bid >> 12, xb = bid & 4095;
        const float* src = z == 0 ? q : z == 1 ? k : v;
        __hip_bfloat16* d = dstIn + (size_t)z * SZ_IN;
        int i = (xb * 256 + tid) * 4;
        float4 val = *(const float4*)(src + i);
        union { __hip_bfloat16 h[4]; uint2 u; } cv;
        cv.h[0] = __float2bfloat16(val.x); cv.h[1] = __float2bfloat16(val.y);
        cv.h[2] = __float2bfloat16(val.z); cv.h[3] = __float2bfloat16(val.w);
        *(uint2*)(d + i) = cv.u;
    } else if (bid < 16384) {
        int r  = bid - 12288;
        int z  = r >> 10, xb = r & 1023;
        const float* src = z == 0 ? wq : z == 1 ? wk : z == 2 ? wv : wo;
        __hip_bfloat16* d = dstW + (size_t)z * SZ_W;
        int i = (xb * 256 + tid) * 4;
        float4 val = *(const float4*)(src + i);
        union { __hip_bfloat16 h[4]; uint2 u; } cv;
        cv.h[0] = __float2bfloat16(val.x); cv.h[1] = __float2bfloat16(val.y);
        cv.h[2] = __float2bfloat16(val.z); cv.h[3] = __float2bfloat16(val.w);
        *(uint2*)(d + i) = cv.u;
    } else {
        int i = ((bid - 16384) * 256 + tid) * 4;   // 4096 ints over 4 blocks
        int4 m = *(const int4*)(mask + i);
        float4 o;
        o.x = m.x ? -100000.0f : 0.0f;
        o.y = m.y ? -100000.0f : 0.0f;
        o.z = m.z ? -100000.0f : 0.0f;
        o.w = m.w ? -100000.0f : 0.0f;
        *(float4*)(fbias + i) = o;
    }
}

// ---------------- GEMM core 128x128: C = A[M,K] @ W[N,K]^T + bias ----------------
// BK=32, 256 threads (4 waves, 64x64 quadrant each), global_load_lds staging.
// 16x16x32 MFMA. R11 lesson: 32x32 frag reads make the 64B-stride LDS rows a 16-way
// bank conflict (vs 8-way here) and regressed ~10 us — keep 16x16 in this structure.
// MODE 0: bf16 row-major. MODE 1: bf16 V^T (Vt[b,h,e,s], packed 8B stores).
template <int MODE>
__device__ __forceinline__ void gemm_core(
    const __hip_bfloat16* __restrict__ A,
    const __hip_bfloat16* __restrict__ W,
    const float* __restrict__ bias,
    void* __restrict__ Cout,
    __hip_bfloat16* __restrict__ smem,   // 2*128*32 bf16
    int m0, int n0, int N)
{
    __hip_bfloat16* As = smem;
    __hip_bfloat16* Bs = smem + 128 * 32;
    const int K = D_;
    const int tid  = threadIdx.x;
    const int wave = tid >> 6;
    const int lane = tid & 63;
    const int quad = lane >> 4;
    const int l15  = lane & 15;
    const int wm   = (wave & 1) * 64;
    const int wn   = (wave >> 1) * 64;
    const int srow = lane >> 2;
    const int scol = (lane & 3) * 8;

    floatx4 acc[4][4];
#pragma unroll
    for (int i = 0; i < 4; i++)
#pragma unroll
        for (int j = 0; j < 4; j++) {
            floatx4 z = {0.f, 0.f, 0.f, 0.f};
            acc[i][j] = z;
        }

    for (int k0 = 0; k0 < K; k0 += 32) {
        __syncthreads();
#pragma unroll
        for (int t = 0; t < 2; t++) {
            int r0 = wave * 32 + t * 16;
            gload_lds16(A + (size_t)(m0 + r0 + srow) * K + k0 + scol, As + r0 * 32);
            gload_lds16(W + (size_t)(n0 + r0 + srow) * K + k0 + scol, Bs + r0 * 32);
        }
        __syncthreads();

        short8 afr[4], bfr[4];
#pragma unroll
        for (int i = 0; i < 4; i++)
            afr[i] = *(const short8*)(As + (wm + i * 16 + l15) * 32 + quad * 8);
#pragma unroll
        for (int j = 0; j < 4; j++)
            bfr[j] = *(const short8*)(Bs + (wn + j * 16 + l15) * 32 + quad * 8);
#pragma unroll
        for (int i = 0; i < 4; i++)
#pragma unroll
            for (int j = 0; j < 4; j++)
                acc[i][j] = mfma32(afr[i], bfr[j], acc[i][j]);
    }

    if constexpr (MODE == 1) {
        // V^T out: Vt[((b*H+h)*64+e)*S + s]; pack r=0..3 (consecutive s) into 8B
#pragma unroll
        for (int j = 0; j < 4; j++) {
            int col = n0 + wn + j * 16 + l15;
            int h = col >> 6, e = col & 63;
            float bv = bias[col];
#pragma unroll
            for (int i = 0; i < 4; i++) {
                int s0 = m0 + wm + i * 16 + quad * 4;
                int bb = s0 >> 11, sl = s0 & 2047;
                union { __hip_bfloat16 hx[4]; uint2 u; } pk;
#pragma unroll
                for (int r = 0; r < 4; r++)
                    pk.hx[r] = __float2bfloat16(acc[i][j][r] + bv);
                *(uint2*)((__hip_bfloat16*)Cout + (((size_t)bb * H_ + h) * HD_ + e) * S_ + sl) = pk.u;
            }
        }
    } else {
#pragma unroll
        for (int j = 0; j < 4; j++) {
            int col = n0 + wn + j * 16 + l15;
            float bv = bias[col];
#pragma unroll
            for (int i = 0; i < 4; i++) {
#pragma unroll
                for (int r = 0; r < 4; r++) {
                    int rowg = m0 + wm + i * 16 + quad * 4 + r;
                    ((__hip_bfloat16*)Cout)[(size_t)rowg * N + col] =
                        __float2bfloat16(acc[i][j][r] + bv);
                }
            }
        }
    }
}

// fused QKV projections: grid (8, 32, 3). XCD-chunked swizzle (T1, proven R7:
// FETCH 69.7 -> 12.4 MB).
__global__ __launch_bounds__(256) void qkv_gemm_kernel(
    const __hip_bfloat16* __restrict__ qb, const __hip_bfloat16* __restrict__ kb,
    const __hip_bfloat16* __restrict__ vb,
    const __hip_bfloat16* __restrict__ Wqb, const __hip_bfloat16* __restrict__ Wkb,
    const __hip_bfloat16* __restrict__ Wvb,
    const float* __restrict__ bq, const float* __restrict__ bk, const float* __restrict__ bv,
    __hip_bfloat16* __restrict__ Qp, __hip_bfloat16* __restrict__ Kp,
    __hip_bfloat16* __restrict__ Vt)
{
    __shared__ __hip_bfloat16 smem[2 * 128 * 32] __attribute__((aligned(16)));
    const int z = blockIdx.z;
    const __hip_bfloat16* A = z == 0 ? qb : z == 1 ? kb : vb;
    const __hip_bfloat16* W = z == 0 ? Wqb : z == 1 ? Wkb : Wvb;
    const float* bias = z == 0 ? bq : z == 1 ? bk : bv;
    int lin  = blockIdx.y * 8 + blockIdx.x;          // 0..255
    int work = (lin & 7) * 32 + (lin >> 3);          // bijective XCD-chunked
    int m0 = (work >> 3) * 128, n0 = (work & 7) * 128;
    if (z < 2) gemm_core<0>(A, W, bias, z == 0 ? (void*)Qp : (void*)Kp, smem, m0, n0, D_);
    else       gemm_core<1>(A, W, bias, (void*)Vt, smem, m0, n0, D_);
}

// ---------------- output projection: 64x128 tile, fp32 out. grid (8, 64) ----------------
__global__ __launch_bounds__(256) void oproj_gemm_kernel(
    const __hip_bfloat16* __restrict__ A, const __hip_bfloat16* __restrict__ W,
    const float* __restrict__ bias, float* __restrict__ out)
{
    __shared__ __hip_bfloat16 As[64 * 32]  __attribute__((aligned(16)));
    __shared__ __hip_bfloat16 Bs[128 * 32] __attribute__((aligned(16)));
    const int K = D_, N = D_;
    const int tid  = threadIdx.x;
    int lin  = blockIdx.y * 8 + blockIdx.x;          // 0..511
    int work = (lin & 7) * 64 + (lin >> 3);          // XCD-chunked swizzle
    const int m0   = (work >> 3) * 64;
    const int n0   = (work & 7) * 128;
    const int wave = tid >> 6;
    const int lane = tid & 63;
    const int quad = lane >> 4;
    const int l15  = lane & 15;
    const int wm   = (wave & 1) * 32;
    const int wn   = (wave >> 1) * 64;
    const int srow = lane >> 2;
    const int scol = (lane & 3) * 8;

    floatx4 acc[2][4];
#pragma unroll
    for (int i = 0; i < 2; i++)
#pragma unroll
        for (int j = 0; j < 4; j++) {
            floatx4 z = {0.f, 0.f, 0.f, 0.f};
            acc[i][j] = z;
        }

    for (int k0 = 0; k0 < K; k0 += 32) {
        __syncthreads();
        {
            int ra = wave * 16;   // A: 64 rows, 1 gload/wave
            gload_lds16(A + (size_t)(m0 + ra + srow) * K + k0 + scol, As + ra * 32);
#pragma unroll
            for (int t = 0; t < 2; t++) {
                int rb = wave * 32 + t * 16;  // B: 128 rows, 2 gloads/wave
                gload_lds16(W + (size_t)(n0 + rb + srow) * K + k0 + scol, Bs + rb * 32);
            }
        }
        __syncthreads();

        short8 afr[2], bfr[4];
#pragma unroll
        for (int i = 0; i < 2; i++)
            afr[i] = *(const short8*)(As + (wm + i * 16 + l15) * 32 + quad * 8);
#pragma unroll
        for (int j = 0; j < 4; j++)
            bfr[j] = *(const short8*)(Bs + (wn + j * 16 + l15) * 32 + quad * 8);
#pragma unroll
        for (int i = 0; i < 2; i++)
#pragma unroll
            for (int j = 0; j < 4; j++)
                acc[i][j] = mfma32(afr[i], bfr[j], acc[i][j]);
    }

#pragma unroll
    for (int j = 0; j < 4; j++) {
        int col = n0 + wn + j * 16 + l15;
        float bv = bias[col];
#pragma unroll
        for (int i = 0; i < 2; i++) {
#pragma unroll
            for (int r = 0; r < 4; r++) {
                int rowg = m0 + wm + i * 16 + quad * 4 + r;
                out[(size_t)rowg * N + col] = acc[i][j][r] + bv;
            }
        }
    }
}

// ---------------- flash attention v11 (R9, proven 52.8 us): R6 + V-frag hoist -----------
// 512 thr = 8 waves (qw=warp&3 q-block, kvh=warp>>2 kv-half), KVBLK=64, 32x32 MFMA,
// swapped QK^T, in-register P (cvt_pk+permlane32_swap), dbuf K/V + reg prefetch, ONE
// barrier per tile, XCD-chunked swizzle, V-frag hoist. Ledger: T15 null (R7), KVBLK=128
// spills (R8), SM->PV split serializes exp2 chains (R10) — this is the local optimum.
#define LDP 72
#define NTK (S_ / 64)
#define KVBUF (64 * LDP)
__global__ __launch_bounds__(512, 4) void flash_attn_kernel(
    const __hip_bfloat16* __restrict__ Q,   // [B,S,D] bf16
    const __hip_bfloat16* __restrict__ Kp,  // [B,S,D] bf16
    const __hip_bfloat16* __restrict__ Vt,  // [B,H,64,S] bf16
    const float* __restrict__ fbias,        // [B,S] additive bias (0 or -1e5)
    __hip_bfloat16* __restrict__ O)         // [B,S,D]
{
    __shared__ __hip_bfloat16 smem[4 * KVBUF] __attribute__((aligned(16)));
    // layout: [0,1) KsB0, [1,2) KsB1, [2,3) VtsB0, [3,4) VtsB1  (units of KVBUF)

    const int tid  = threadIdx.x;
    int lin  = blockIdx.y * 16 + blockIdx.x;        // 0..511
    int work = (lin & 7) * 64 + (lin >> 3);         // XCD-chunked swizzle
    const int q0   = (work & 15) * 128;
    const int bh   = work >> 4;
    const int b    = bh >> 4;
    const int h    = bh & 15;
    const int warp = tid >> 6;
    const int qw   = warp & 3;     // q-block
    const int kvh  = warp >> 2;    // kv half of each tile
    const int lane = tid & 63;
    const int l31  = lane & 31;
    const int hi   = lane >> 5;
    const float kSc = 0.18033688f;  // 0.125 * log2(e)

    // ---- stage Q (128x64) coalesced into smem base, read frags, release ----
    const size_t baseQ = ((size_t)b * S_ + q0) * D_ + (size_t)h * HD_;
#pragma unroll
    for (int c = tid; c < 1024; c += 512) {
        int row = c >> 3, kc = c & 7;
        *(uint4*)(smem + row * LDP + kc * 8) =
            *(const uint4*)(Q + baseQ + (size_t)row * D_ + kc * 8);
    }
    __syncthreads();
    short8 qb[4];   // B-frag: n=q=l31, k(hd) = ks*16 + hi*8 + j
#pragma unroll
    for (int ks = 0; ks < 4; ks++)
        qb[ks] = *(const short8*)(smem + (qw * 32 + l31) * LDP + ks * 16 + hi * 8);
    __syncthreads();   // all frag reads done before staging overwrites smem

    const float* brow = fbias + b * S_;
    const __hip_bfloat16* VtBase = Vt + (size_t)bh * HD_ * S_;
    const size_t baseKrow = (size_t)b * S_ * D_ + (size_t)h * HD_;

    // prefetch staging: 512 threads cover one 64x64 tile of K and of Vt, 1 uint4 each
    const int r0  = tid >> 3;          // 0..63
    const int kc0 = (tid & 7) * 8;

    uint4 kreg, vreg;
    auto issue = [&](int kv0) {
        kreg = *(const uint4*)(Kp + baseKrow + (size_t)(kv0 + r0) * D_ + kc0);
        vreg = *(const uint4*)(VtBase + (size_t)r0 * S_ + kv0 + kc0);
    };
    auto commit = [&](int pb) {
        *(uint4*)(smem + pb * KVBUF + r0 * LDP + kc0) = kreg;
        *(uint4*)(smem + (2 + pb) * KVBUF + r0 * LDP + kc0) = vreg;
    };

    issue(0);
    commit(0);
    __syncthreads();

    float lsum = 0.f;
    f32x16 o_acc[2];
#pragma unroll
    for (int hdb = 0; hdb < 2; hdb++)
#pragma unroll
        for (int r = 0; r < 16; r++) o_acc[hdb][r] = 0.f;

    for (int t = 0; t < NTK; ++t) {
        if (t) __syncthreads();   // buf[t&1] commits visible; prev readers ordered

        if (t + 1 < NTK) issue((t + 1) * 64);

        const __hip_bfloat16* Ks  = smem + (t & 1) * KVBUF;
        const __hip_bfloat16* Vts = smem + (2 + (t & 1)) * KVBUF;

        // hoist V B-frags: 4 independent ds_reads that complete under the QK chain
        short8 vfr[4];
#pragma unroll
        for (int hdb = 0; hdb < 2; hdb++)
#pragma unroll
            for (int ksl = 0; ksl < 2; ksl++)
                vfr[hdb * 2 + ksl] = *(const short8*)(Vts + (hdb * 32 + l31) * LDP +
                                                      kvh * 32 + ksl * 16 + hi * 8);

        // S^T = K.Q^T for this wave's kv half: 4 chained MFMAs
        f32x16 z;
#pragma unroll
        for (int r = 0; r < 16; r++) z[r] = 0.f;
        __builtin_amdgcn_s_setprio(1);
#pragma unroll
        for (int ks = 0; ks < 4; ks++) {
            short8 ka = *(const short8*)(Ks + (kvh * 32 + l31) * LDP + ks * 16 + hi * 8);
            z = mfma3216(ka, qb[ks], z);
        }
        __builtin_amdgcn_s_setprio(0);

        // softmax numerator + pack, 8 values (one 16-kv slice) at a time
        short8 pa[2];
#pragma unroll
        for (int ksl = 0; ksl < 2; ksl++) {
            // bias: p[i] needs kv = t*64 + kvh*32 + ksl*16 + (i>>2)*8 + (i&3) + 4*hi
            const float* bb = brow + t * 64 + kvh * 32 + ksl * 16 + hi * 4;
            floatx4 b0 = *(const floatx4*)(bb);
            floatx4 b1 = *(const floatx4*)(bb + 8);
            float p[8];
#pragma unroll
            for (int i = 0; i < 8; i++) {
                float bias = (i < 4) ? b0[i & 3] : b1[i & 3];
                p[i] = __builtin_amdgcn_exp2f(z[ksl * 8 + i] * kSc + bias);
            }
            lsum += ((p[0] + p[1]) + (p[2] + p[3])) + ((p[4] + p[5]) + (p[6] + p[7]));
            int w0 = pkbf(p[0], p[1]);
            int w2 = pkbf(p[4], p[5]);
            int w1 = pkbf(p[2], p[3]);
            int w3 = pkbf(p[6], p[7]);
            pl32swap(w0, w2);
            pl32swap(w1, w3);
            union { int w[4]; short8 s; } fr;
            fr.w[0] = w0; fr.w[1] = w1; fr.w[2] = w2; fr.w[3] = w3;
            pa[ksl] = fr.s;
        }

        // O += P @ V over this kv half: operands already in registers (vfr)
        __builtin_amdgcn_s_setprio(1);
#pragma unroll
        for (int hdb = 0; hdb < 2; hdb++)
#pragma unroll
            for (int ksl = 0; ksl < 2; ksl++)
                o_acc[hdb] = mfma3216(pa[ksl], vfr[hdb * 2 + ksl], o_acc[hdb]);
        __builtin_amdgcn_s_setprio(0);

        if (t + 1 < NTK) commit((t + 1) & 1);   // safe: prev readers barrier-ordered
    }

    // ---- combine kv-half partials across wave pairs (w, w+4) via LDS ----
    __syncthreads();   // all LDS tile reads done; smem reusable as scratch
    float* ored = (float*)smem;            // [32 slots][256 lanes] = 32 KB
    float* lred = (float*)smem + 8192;     // [256]
    if (kvh == 1) {
#pragma unroll
        for (int hdb = 0; hdb < 2; hdb++)
#pragma unroll
            for (int r = 0; r < 16; r++)
                ored[(hdb * 16 + r) * 256 + qw * 64 + lane] = o_acc[hdb][r];
        lred[qw * 64 + lane] = lsum;
    }
    __syncthreads();
    if (kvh == 0) {
#pragma unroll
        for (int hdb = 0; hdb < 2; hdb++)
#pragma unroll
            for (int r = 0; r < 16; r++)
                o_acc[hdb][r] += ored[(hdb * 16 + r) * 256 + qw * 64 + lane];
        float ls = lsum + lred[qw * 64 + lane];
        ls += __shfl_xor(ls, 32);
        float inv = 1.0f / ls;

        const size_t baseO = ((size_t)b * S_ + q0 + qw * 32) * D_ + (size_t)h * HD_;
#pragma unroll
        for (int r = 0; r < 16; r++) {
            int crow = (r & 3) + 8 * (r >> 2) + 4 * hi;   // q row for this reg
            float iv = __shfl(inv, crow);
#pragma unroll
            for (int hdb = 0; hdb < 2; hdb++)
                O[baseO + (size_t)crow * D_ + hdb * 32 + l31] =
                    __float2bfloat16(o_acc[hdb][r] * iv);
        }
    }
}

extern "C" void kernel_launch(void* const* d_in, const int* in_sizes, int n_in,
                              void* d_out, int out_size, void* d_ws, size_t ws_size,
                              hipStream_t stream) {
    const float* query = (const float*)d_in[0];
    const float* key   = (const float*)d_in[1];
    const float* value = (const float*)d_in[2];
    const int*   mask  = (const int*)d_in[3];
    const float* Wq    = (const float*)d_in[4];
    const float* bq    = (const float*)d_in[5];
    const float* Wk    = (const float*)d_in[6];
    const float* bk    = (const float*)d_in[7];
    const float* Wv    = (const float*)d_in[8];
    const float* bv    = (const float*)d_in[9];
    const float* Wo    = (const float*)d_in[10];
    const float* bo    = (const float*)d_in[11];
    float* out = (float*)d_out;

    const size_t SZ_IN = (size_t)M_ * D_;
    const size_t SZ_W  = (size_t)D_ * D_;
    __hip_bfloat16* qb  = (__hip_bfloat16*)d_ws;
    __hip_bfloat16* kb  = qb  + SZ_IN;
    __hip_bfloat16* vb  = kb  + SZ_IN;
    __hip_bfloat16* Wqb = vb  + SZ_IN;
    __hip_bfloat16* Wkb = Wqb + SZ_W;
    __hip_bfloat16* Wvb = Wkb + SZ_W;
    __hip_bfloat16* Wob = Wvb + SZ_W;
    __hip_bfloat16* Qp  = Wob + SZ_W;
    __hip_bfloat16* Kp  = Qp  + SZ_IN;
    __hip_bfloat16* Vt  = Kp  + SZ_IN;      // [B,H,64,S]
    float*          fb  = (float*)(Vt + SZ_IN);  // [B,S] additive softmax bias

    cvt_all_kernel<<<dim3(16388), 256, 0, stream>>>(
        query, key, value, Wq, Wk, Wv, Wo, mask, qb, Wqb, fb);

    qkv_gemm_kernel<<<dim3(D_ / 128, M_ / 128, 3), 256, 0, stream>>>(
        qb, kb, vb, Wqb, Wkb, Wvb, bq, bk, bv, Qp, Kp, Vt);

    flash_attn_kernel<<<dim3(S_ / 128, B_ * H_), 512, 0, stream>>>(Qp, Kp, Vt, fb, Qp);

    oproj_gemm_kernel<<<dim3(D_ / 128, M_ / 64), 256, 0, stream>>>(Qp, Wob, bo, out);
}